// Round 13
// baseline (198.027 us; speedup 1.0000x reference)
//
#include <hip/hip_runtime.h>
#include <hip/hip_bf16.h>
#include <stdint.h>

typedef float f32x4 __attribute__((ext_vector_type(4)));
typedef __bf16 bf16x8 __attribute__((ext_vector_type(8)));

#define GLDS16(gp, lp) __builtin_amdgcn_global_load_lds( \
    (const __attribute__((address_space(1))) void*)(gp), \
    (__attribute__((address_space(3))) void*)(lp), 16, 0, 0)

static __device__ __forceinline__ unsigned short f2bf(float f) {
    unsigned int u = __float_as_uint(f);
    u = (u + 0x7fffu + ((u >> 16) & 1u)) >> 16;
    return (unsigned short)u;
}
static __device__ __forceinline__ float bf2f(unsigned short v) {
    return __uint_as_float(((unsigned int)v) << 16);
}

// ---------------- workspace layout (bytes) ----------------
// styles : 16x512 f32                          @ 0
// dcoefs : 16x512 f32                          @ 32768
// xs_pad : 16x34x34x512 bf16 (NHWC, +1 halo)   @ 65536      (18.06 MB)
// wp     : 9x512x512 bf16 ([tap][co][ci])      @ 19005440   (4.5 MB)
// y1T    : 16x4x512x1104 bf16 ([b][pl][co][pix]) @ 23724032 (72.35 MB)
// wsq    : 512x512 f32 — OVERLAPPED into y1T region (consumed before y1 written)
#define O_STYLES 0
#define O_DCOEF  32768
#define O_XS     65536
#define O_WP     19005440
#define O_Y1     23724032
#define O_WSQ    23724032
#define WS_NEED  96075776
#define SP 1104   // y1T pixel stride per co row (2208 B, 32B-aligned rows)
// conv M axis: gm = b*1092 + pix (pix<1089 real, 1089..1091 junk), M=17472
// Zero-invariants (used by k_blur verbatim staging + clean conv epilogue):
//  odd-col/odd-row parities read the zeroed xs halo for s==32 / r==32 -> 0.

// K_PA: fused k_styles (0..31) + k_wprep (32..1055) + xs halo-zero (1056..1071).
__global__ __launch_bounds__(256) void k_prepA(const float* __restrict__ w,
                                               const float* __restrict__ aw,
                                               const float* __restrict__ ab,
                                               const float* __restrict__ weight,
                                               float* __restrict__ styles,
                                               float* __restrict__ wsq,
                                               unsigned short* __restrict__ wp,
                                               unsigned short* __restrict__ xs) {
    int bid = blockIdx.x;
    int t = threadIdx.x;
    if (bid < 32) {
        // styles[b][ci] = w[b]·A[ci]/sqrt(512) + bias[ci]
        int g = bid * 256 + t;   // 8192
        int b = g >> 9, ci = g & 511;
        const float4* wr = (const float4*)(w + b * 512);
        const float4* ar = (const float4*)(aw + ci * 512);
        float acc = 0.f;
        for (int k = 0; k < 128; ++k) {
            float4 wv = wr[k], av = ar[k];
            acc += wv.x * av.x + wv.y * av.y + wv.z * av.z + wv.w * av.w;
        }
        styles[g] = acc * 0.04419417382415922f + ab[ci];
    } else if (bid < 1056) {
        // per (co,ci): wsq = sum of 9 squared taps; wp[tap][co][ci] = bf16(tap)
        int g = (bid - 32) * 256 + t;   // 262144 = co*512+ci
        const float* wb = weight + (long)g * 9;
        float v[9]; float s = 0.f;
#pragma unroll
        for (int q = 0; q < 9; ++q) { v[q] = wb[q]; s += v[q] * v[q]; }
        wsq[g] = s;
        // tap order: par0 (ee): (2,2)(2,0)(0,2)(0,0); par1 (eo): (2,1)(0,1);
        // par2 (oe): (1,2)(1,0); par3 (oo): (1,1)
        const int wri[9] = {2, 2, 0, 0, 2, 0, 1, 1, 1};
        const int wci[9] = {2, 0, 2, 0, 1, 1, 2, 0, 1};
#pragma unroll
        for (int q = 0; q < 9; ++q)
            wp[q * 262144 + g] = f2bf(v[wri[q] * 3 + wci[q]]);
    } else {
        // xs halo zero: one block per b; 132 halo positions x 512 ch.
        int b = bid - 1056;
        for (int it = 0; it < 66; ++it) {
            int idx = t + it * 256;                // 0..16895
            int pos = idx >> 7, q = idx & 127;     // 128 ushort4 per position
            int r, c;
            if (pos < 34)       { r = 0;         c = pos; }
            else if (pos < 68)  { r = 33;        c = pos - 34; }
            else if (pos < 100) { r = pos - 67;  c = 0; }
            else                { r = pos - 99;  c = 33; }
            ushort4 z = {0, 0, 0, 0};
            *(ushort4*)(xs + (((long)(b * 34 + r)) * 34 + c) * 512 + q * 4) = z;
        }
    }
}

// K_PB: fused k_dcoef (blocks 0..31) + k_xprep (blocks 32..2079, float4 reads).
__global__ __launch_bounds__(256) void k_prepB(const float* __restrict__ styles,
                                               const float* __restrict__ wsq,
                                               const float* __restrict__ x,
                                               float* __restrict__ dcoefs,
                                               unsigned short* __restrict__ xs) {
    __shared__ float T[128][33];
    int bid = blockIdx.x;
    int t = threadIdx.x;
    if (bid < 32) {
        int g = bid * 256 + t;   // 8192
        int b = g >> 9, co = g & 511;
        const float4* sr = (const float4*)(styles + b * 512);
        const float4* qr = (const float4*)(wsq + co * 512);
        float acc = 1e-8f;
        for (int k = 0; k < 128; ++k) {
            float4 sv = sr[k], qv = qr[k];
            acc += sv.x * sv.x * qv.x + sv.y * sv.y * qv.y + sv.z * sv.z * qv.z + sv.w * sv.w * qv.w;
        }
        dcoefs[g] = rsqrtf(acc);
        return;
    }
    int xb = bid - 32;                    // 16*32*4
    int cc = xb & 3, i = (xb >> 2) & 31, b = xb >> 7;
    int ci0 = cc * 128;
    int j4 = (t & 7) * 4, cl_r = t >> 3;
    const float* xp = x + (((long)(b * 512 + ci0)) * 32 + i) * 32;
#pragma unroll
    for (int it = 0; it < 4; ++it) {
        int cl = cl_r + it * 32;
        float4 v = *(const float4*)(xp + cl * 1024 + j4);
        T[cl][j4] = v.x; T[cl][j4 + 1] = v.y; T[cl][j4 + 2] = v.z; T[cl][j4 + 3] = v.w;
    }
    __syncthreads();
    int ci_w = t & 127, jg = t >> 7;
    float sv = styles[b * 512 + ci0 + ci_w];
    unsigned short* op = xs + (((long)(b * 34 + (i + 1))) * 34 + 1) * 512 + ci0 + ci_w;
#pragma unroll
    for (int jj = 0; jj < 16; ++jj) {
        int j = jg * 16 + jj;
        op[(long)j * 512] = f2bf(T[ci_w][j] * sv);
    }
}

// K5: stage-1 implicit GEMM, 128x128 tile, BK=64, 4 waves (2Mx2N), 256 thr.
// Same proven phase discipline as the 256² R8 kernel (counted vmcnt(4), lgkm
// drain + sched_barrier before 16-MFMA cluster, setprio, tail barrier) but
// LDS = 64KB (2 bufs x {A-k0,A-k1,B-k0,B-k1} 8KB) -> 2 blocks/CU co-resident
// (VGPR ~125/wave, cap 256 at 2 waves/SIMD — no spill mode exists). The
// second block fills this structure's ~70% drain time (m114 overlap).
// Grid 2192 = 548 jobs (par-major, heavy-first) x 4 Ntiles; remap keeps the
// 4 Ntile-siblings of a job on one XCD (same d mod 8) for A-tile L2 reuse.
#define ST_A(kk) { GLDS16(xsB + sA0 + akt + (kk)*64, smp + nb + (kk)*8192 + t16); \
                   GLDS16(xsB + sA1 + akt + (kk)*64, smp + nb + (kk)*8192 + t16 + 4096); }
#define ST_B(kk) { GLDS16(wpB + sB0 + bkt + (kk)*64, smp + nb + 16384 + (kk)*8192 + t16); \
                   GLDS16(wpB + sB1 + bkt + (kk)*64, smp + nb + 16384 + (kk)*8192 + t16 + 4096); }
#define PHASE2(kk, STG, TAILBAR) { \
  _Pragma("unroll") for (int i = 0; i < 4; ++i) \
    av[i] = *(const bf16x8*)(smp + cb + (kk)*8192 + abase + (i*16)*64); \
  _Pragma("unroll") for (int j = 0; j < 4; ++j) \
    bv[j] = *(const bf16x8*)(smp + cb + 16384 + (kk)*8192 + bbase + (j*16)*64); \
  STG; \
  __builtin_amdgcn_sched_barrier(0); \
  asm volatile("s_waitcnt vmcnt(4)" ::: "memory"); \
  __builtin_amdgcn_s_barrier(); \
  asm volatile("s_waitcnt lgkmcnt(0)" ::: "memory"); \
  __builtin_amdgcn_sched_barrier(0); \
  __builtin_amdgcn_s_setprio(1); \
  _Pragma("unroll") for (int i = 0; i < 4; ++i) \
    _Pragma("unroll") for (int j = 0; j < 4; ++j) \
      acc[i][j] = __builtin_amdgcn_mfma_f32_16x16x32_bf16(av[i], bv[j], acc[i][j], 0, 0, 0); \
  __builtin_amdgcn_s_setprio(0); \
  if (TAILBAR) __builtin_amdgcn_s_barrier(); }

__global__ __launch_bounds__(256) void k_conv(const unsigned short* __restrict__ xs,
                                              const unsigned short* __restrict__ wp,
                                              unsigned short* __restrict__ y1) {
    extern __shared__ __align__(16) char smem[];
    const unsigned char* xsB = (const unsigned char*)xs;
    const unsigned char* wpB = (const unsigned char*)wp;
    char* smp = smem;

    // decode: d -> job j (par-major) + Ntile; siblings share d mod 8 (one XCD)
    int d = blockIdx.x;
    int j, nt2;
    if (d < 2176) { int g = d >> 5, r = d & 31; j = g * 8 + (r & 7); nt2 = r >> 3; }
    else          { int r = d - 2176; j = 544 + (r & 3); nt2 = r >> 2; }
    int par = j / 137;
    int Mtile = j - par * 137;
    int Ntile = nt2;
    int a_par = par >> 1, c_par = par & 1;
    int ntaps = a_par ? (c_par ? 1 : 2) : (c_par ? 2 : 4);
    int tapofs = (par == 0) ? 0 : ((par == 1) ? 4 : ((par == 2) ? 6 : 8));
    int NKT = ntaps << 3;                 // K-tiles of 64 ci

    int tid = threadIdx.x;
    int lane = tid & 63, wave = tid >> 6;
    int wm = wave >> 1, wn = wave & 1;
    int lrow = lane & 15;
    int rchunk = (((lane >> 4) ^ ((lrow >> 1) & 3)) << 4);   // swizzled read chunk
    int abase = (wm * 64 + lrow) * 64 + rchunk;
    int bbase = (wn * 64 + lrow) * 64 + rchunk;

    // staging source bases (rows tid>>2 and +64 of the 128-row tile)
    int srow = tid >> 2;
    int schunk = (((tid & 3) ^ ((tid >> 3) & 3)) << 4);      // inverse-swizzled source chunk
    int sA0, sA1;
    {
        unsigned gm = (unsigned)(Mtile * 128 + srow);
        if (gm > 17471u) gm = 17471u;
        unsigned b_ = gm / 1092u; unsigned pix = gm - b_ * 1092u;
        unsigned r = pix / 33u; unsigned s = pix - r * 33u;
        sA0 = (int)(((b_ * 34u + r) * 34u + s) << 10) + schunk;
        gm = (unsigned)(Mtile * 128 + srow + 64);
        if (gm > 17471u) gm = 17471u;
        b_ = gm / 1092u; pix = gm - b_ * 1092u;
        r = pix / 33u; s = pix - r * 33u;
        sA1 = (int)(((b_ * 34u + r) * 34u + s) << 10) + schunk;
    }
    int sB0 = ((Ntile * 128 + srow) << 10) + schunk;
    int sB1 = sB0 + (64 << 10);
    int t16 = tid << 4;

    f32x4 acc[4][4];
#pragma unroll
    for (int i = 0; i < 4; ++i)
#pragma unroll
        for (int j2 = 0; j2 < 4; ++j2)
            acc[i][j2] = (f32x4){0.f, 0.f, 0.f, 0.f};
    bf16x8 av[4], bv[4];

    auto mkA = [&](int kt) -> int {
        int tl = kt >> 3; if (tl >= ntaps) tl = ntaps - 1;
        int cib = kt & 7;
        int dio = a_par ? 1 : (c_par ? tl : (tl >> 1));
        int djo = c_par ? 1 : (a_par ? tl : (tl & 1));
        return dio * 34816 + djo * 1024 + cib * 128;
    };
    auto mkB = [&](int kt) -> long {
        int tl = kt >> 3; if (tl >= ntaps) tl = ntaps - 1;
        return (long)(tapofs + tl) * 524288 + (long)((kt & 7) * 128);
    };

    // prologue: stage K-tile 0 into buf0 (order A0,B0,A1,B1 — vmcnt counting)
    {
        int akt = mkA(0); long bkt = mkB(0); int nb = 0;
        ST_A(0); ST_B(0); ST_A(1); ST_B(1);
    }
    __builtin_amdgcn_sched_barrier(0);
    asm volatile("s_waitcnt vmcnt(4)" ::: "memory");   // k0 halves of tile 0 ready
    __builtin_amdgcn_s_barrier();

    int cur = 0;
    for (int kt = 0; kt < NKT; ++kt) {
        int akt = mkA(kt + 1);
        long bkt = mkB(kt + 1);
        int nb = (cur ^ 1) << 15;
        int cb = cur << 15;
        PHASE2(0, { ST_A(0); ST_B(0); }, 0)
        PHASE2(1, { ST_A(1); ST_B(1); }, 1)
        cur ^= 1;
    }
    // drain dangling prefetch: with 2 blocks/CU this block's LDS is reallocated
    // at exit; an in-flight global_load_lds landing late would corrupt it.
    asm volatile("s_waitcnt vmcnt(0)" ::: "memory");

    // epilogue: clean unconditional ushort4 stores (junk cells are naturally 0).
#pragma unroll
    for (int mf = 0; mf < 4; ++mf) {
        int gm0 = Mtile * 128 + wm * 64 + mf * 16 + ((lane >> 4) << 2);
        if (gm0 < 17472) {
            unsigned ug = (unsigned)gm0;
            unsigned bb = ug / 1092u;
            int pix0 = (int)(ug - bb * 1092u);          // multiple of 4
            long rowb = ((long)((bb * 4u + par) * 512)) * SP;
#pragma unroll
            for (int nf = 0; nf < 4; ++nf) {
                int co = Ntile * 128 + wn * 64 + nf * 16 + lrow;
                unsigned short* dst = y1 + rowb + (long)co * SP + pix0;
                if (pix0 <= 1084) {
                    ushort4 pk;
                    pk.x = f2bf(acc[mf][nf][0]);
                    pk.y = f2bf(acc[mf][nf][1]);
                    pk.z = f2bf(acc[mf][nf][2]);
                    pk.w = f2bf(acc[mf][nf][3]);
                    *(ushort4*)dst = pk;
                } else if (pix0 == 1088) {
                    dst[0] = f2bf(acc[mf][nf][0]);
                }
            }
        }
    }
}

// K6: blur(4x4 bilinear, separable) + demod + noise + bias + leaky.
// LINEAR plane staging (R12-proven): yl[pl][p], p = r*33+s.
__global__ __launch_bounds__(256) void k_blur(const unsigned short* __restrict__ y1,
                                              const float* __restrict__ dcoefs,
                                              const float* __restrict__ bias,
                                              const float* __restrict__ noise,
                                              const float* __restrict__ nstr,
                                              float* __restrict__ out) {
    __shared__ float yl[4 * 1092];        // 17472 B
    int bid = blockIdx.x;                 // 2048 = 16 b * 128 cg
    int cg = bid & 127, b = bid >> 7;
    int t = threadIdx.x;
    int n = t & 63, mq = t >> 6;
    float ns = nstr[0];

    const float* npb = noise + b * 4096;

    int o = n & 1;
    int se = n >> 1;
    int sp_ = se - 1 + o;                 // -1 only for n==0
    float a0 = o ? 1.f : 3.f;
    float a1 = o ? 3.f : 1.f;

    for (int cc = 0; cc < 4; ++cc) {
        int co = cg * 4 + cc;
#pragma unroll
        for (int pl = 0; pl < 4; ++pl) {
            const unsigned short* src = y1 + ((long)((b * 4 + pl) * 512 + co)) * SP;
            float* dst = yl + pl * 1092;
            for (int it = t; it < 273; it += 256) {
                int p0 = it * 4;
                ushort4 v = *(const ushort4*)(src + p0);   // 8B aligned
                f32x4 fv;
                fv[0] = bf2f(v.x); fv[1] = bf2f(v.y);
                fv[2] = bf2f(v.z); fv[3] = bf2f(v.w);
                *(f32x4*)(dst + p0) = fv;                  // 16B aligned
            }
        }
        __syncthreads();

        float dc = dcoefs[b * 512 + co];
        float bi = bias[co];
        float* ob = out + ((long)(b * 512 + co)) * 4096;

        auto H = [&](int ap, int r) -> float {
            if ((unsigned)r > 32u) return 0.f;            // rows -1 / 33
            const float* pe = yl + (ap * 2) * 1092 + r * 33;
            const float* po = pe + 1092;
            float pov = (sp_ >= 0) ? po[sp_] : 0.f;       // col -1 (n==0 only)
            return a0 * pe[se] + a1 * pe[se + 1] + a1 * pov + a0 * po[sp_ + 1];
        };

        int m0 = mq * 16;                 // even
        int re = m0 >> 1;
        float he0 = H(0, re), he1 = H(0, re + 1);
        float ho0 = H(1, re - 1), ho1 = H(1, re);
#pragma unroll
        for (int k = 0; k < 16; k += 2) {
            int m = m0 + k;
            float ve = 3.f * he0 + he1 + ho0 + 3.f * ho1;
            float val = npb[m * 64 + n] * ns + ve * (0.0625f * dc);
            val = (val + bi) * 1.41421356237309515f;
            ob[m * 64 + n] = (val >= 0.f) ? val : 0.2f * val;
            float hn_o = H(1, re + 1);
            float vo = he0 + 3.f * he1 + 3.f * ho1 + hn_o;
            val = npb[(m + 1) * 64 + n] * ns + vo * (0.0625f * dc);
            val = (val + bi) * 1.41421356237309515f;
            ob[(m + 1) * 64 + n] = (val >= 0.f) ? val : 0.2f * val;
            ho0 = ho1; ho1 = hn_o;
            float hn_e = H(0, re + 2);
            he0 = he1; he1 = hn_e;
            re += 1;
        }
        __syncthreads();
    }
}

extern "C" void kernel_launch(void* const* d_in, const int* in_sizes, int n_in,
                              void* d_out, int out_size, void* d_ws, size_t ws_size,
                              hipStream_t stream) {
    (void)in_sizes; (void)n_in; (void)out_size;
    if (ws_size < (size_t)WS_NEED) return;   // workspace too small: fail cleanly
    const float* x      = (const float*)d_in[0];
    const float* w      = (const float*)d_in[1];
    const float* noise  = (const float*)d_in[2];
    const float* aw     = (const float*)d_in[3];
    const float* ab     = (const float*)d_in[4];
    const float* weight = (const float*)d_in[5];
    const float* bias   = (const float*)d_in[6];
    const float* nstr   = (const float*)d_in[7];
    float* out = (float*)d_out;
    char* ws = (char*)d_ws;
    float* styles          = (float*)(ws + O_STYLES);
    float* dcoefs          = (float*)(ws + O_DCOEF);
    unsigned short* xs     = (unsigned short*)(ws + O_XS);
    unsigned short* wp     = (unsigned short*)(ws + O_WP);
    unsigned short* y1     = (unsigned short*)(ws + O_Y1);
    float* wsq             = (float*)(ws + O_WSQ);   // overlapped with y1 head

    hipFuncSetAttribute((const void*)k_conv,
                        hipFuncAttributeMaxDynamicSharedMemorySize, 65536);

    k_prepA<<<1072, 256, 0, stream>>>(w, aw, ab, weight, styles, wsq, wp, xs);
    k_prepB<<<2080, 256, 0, stream>>>(styles, wsq, x, dcoefs, xs);
    k_conv <<<2192, 256, 65536, stream>>>(xs, wp, y1);
    k_blur <<<2048, 256, 0, stream>>>(y1, dcoefs, bias, noise, nstr, out);
}

// Round 14
// 186.444 us; speedup vs baseline: 1.0621x; 1.0621x over previous
//
#include <hip/hip_runtime.h>
#include <hip/hip_bf16.h>
#include <stdint.h>

typedef float f32x4 __attribute__((ext_vector_type(4)));
typedef __bf16 bf16x8 __attribute__((ext_vector_type(8)));

#define GLDS16(gp, lp) __builtin_amdgcn_global_load_lds( \
    (const __attribute__((address_space(1))) void*)(gp), \
    (__attribute__((address_space(3))) void*)(lp), 16, 0, 0)

static __device__ __forceinline__ unsigned short f2bf(float f) {
    unsigned int u = __float_as_uint(f);
    u = (u + 0x7fffu + ((u >> 16) & 1u)) >> 16;
    return (unsigned short)u;
}
static __device__ __forceinline__ float bf2f(unsigned short v) {
    return __uint_as_float(((unsigned int)v) << 16);
}

// ---------------- workspace layout (bytes) ----------------
// styles : 16x512 f32                          @ 0
// dcoefs : 16x512 f32                          @ 32768
// xs_pad : 16x34x34x512 bf16 (NHWC, +1 halo)   @ 65536      (18.06 MB)
// wp     : 9x512x512 bf16 ([tap][co][ci])      @ 19005440   (4.5 MB)
// y1T    : 16x4x512x1104 bf16 ([b][pl][co][pix]) @ 23724032 (72.35 MB)
// wsq    : 512x512 f32 — OVERLAPPED into y1T region (consumed before y1 written)
#define O_STYLES 0
#define O_DCOEF  32768
#define O_XS     65536
#define O_WP     19005440
#define O_Y1     23724032
#define O_WSQ    23724032
#define WS_NEED  96075776
#define SP 1104   // y1T pixel stride per co row (2208 B, 32B-aligned rows)
// conv M axis: gm = b*1092 + pix (pix<1089 real, 1089..1091 junk), M=17472
// Zero-invariants (used by k_blur verbatim staging + clean conv epilogue):
//  odd-col/odd-row parities read the zeroed xs halo for s==32 / r==32 -> 0.

// K_PA: fused k_styles (0..31) + k_wprep (32..1055) + xs halo-zero (1056..1071).
__global__ __launch_bounds__(256) void k_prepA(const float* __restrict__ w,
                                               const float* __restrict__ aw,
                                               const float* __restrict__ ab,
                                               const float* __restrict__ weight,
                                               float* __restrict__ styles,
                                               float* __restrict__ wsq,
                                               unsigned short* __restrict__ wp,
                                               unsigned short* __restrict__ xs) {
    int bid = blockIdx.x;
    int t = threadIdx.x;
    if (bid < 32) {
        // styles[b][ci] = w[b]·A[ci]/sqrt(512) + bias[ci]
        int g = bid * 256 + t;   // 8192
        int b = g >> 9, ci = g & 511;
        const float4* wr = (const float4*)(w + b * 512);
        const float4* ar = (const float4*)(aw + ci * 512);
        float acc = 0.f;
        for (int k = 0; k < 128; ++k) {
            float4 wv = wr[k], av = ar[k];
            acc += wv.x * av.x + wv.y * av.y + wv.z * av.z + wv.w * av.w;
        }
        styles[g] = acc * 0.04419417382415922f + ab[ci];
    } else if (bid < 1056) {
        // per (co,ci): wsq = sum of 9 squared taps; wp[tap][co][ci] = bf16(tap)
        int g = (bid - 32) * 256 + t;   // 262144 = co*512+ci
        const float* wb = weight + (long)g * 9;
        float v[9]; float s = 0.f;
#pragma unroll
        for (int q = 0; q < 9; ++q) { v[q] = wb[q]; s += v[q] * v[q]; }
        wsq[g] = s;
        // tap order: par0 (ee): (2,2)(2,0)(0,2)(0,0); par1 (eo): (2,1)(0,1);
        // par2 (oe): (1,2)(1,0); par3 (oo): (1,1)
        const int wri[9] = {2, 2, 0, 0, 2, 0, 1, 1, 1};
        const int wci[9] = {2, 0, 2, 0, 1, 1, 2, 0, 1};
#pragma unroll
        for (int q = 0; q < 9; ++q)
            wp[q * 262144 + g] = f2bf(v[wri[q] * 3 + wci[q]]);
    } else {
        // xs halo zero: one block per b; 132 halo positions x 512 ch.
        int b = bid - 1056;
        for (int it = 0; it < 66; ++it) {
            int idx = t + it * 256;                // 0..16895
            int pos = idx >> 7, q = idx & 127;     // 128 ushort4 per position
            int r, c;
            if (pos < 34)       { r = 0;         c = pos; }
            else if (pos < 68)  { r = 33;        c = pos - 34; }
            else if (pos < 100) { r = pos - 67;  c = 0; }
            else                { r = pos - 99;  c = 33; }
            ushort4 z = {0, 0, 0, 0};
            *(ushort4*)(xs + (((long)(b * 34 + r)) * 34 + c) * 512 + q * 4) = z;
        }
    }
}

// K_PB: fused k_dcoef (blocks 0..31) + k_xprep (blocks 32..2079, float4 reads).
__global__ __launch_bounds__(256) void k_prepB(const float* __restrict__ styles,
                                               const float* __restrict__ wsq,
                                               const float* __restrict__ x,
                                               float* __restrict__ dcoefs,
                                               unsigned short* __restrict__ xs) {
    __shared__ float T[128][33];
    int bid = blockIdx.x;
    int t = threadIdx.x;
    if (bid < 32) {
        int g = bid * 256 + t;   // 8192
        int b = g >> 9, co = g & 511;
        const float4* sr = (const float4*)(styles + b * 512);
        const float4* qr = (const float4*)(wsq + co * 512);
        float acc = 1e-8f;
        for (int k = 0; k < 128; ++k) {
            float4 sv = sr[k], qv = qr[k];
            acc += sv.x * sv.x * qv.x + sv.y * sv.y * qv.y + sv.z * sv.z * qv.z + sv.w * sv.w * qv.w;
        }
        dcoefs[g] = rsqrtf(acc);
        return;
    }
    int xb = bid - 32;                    // 16*32*4
    int cc = xb & 3, i = (xb >> 2) & 31, b = xb >> 7;
    int ci0 = cc * 128;
    int j4 = (t & 7) * 4, cl_r = t >> 3;
    const float* xp = x + (((long)(b * 512 + ci0)) * 32 + i) * 32;
#pragma unroll
    for (int it = 0; it < 4; ++it) {
        int cl = cl_r + it * 32;
        float4 v = *(const float4*)(xp + cl * 1024 + j4);
        T[cl][j4] = v.x; T[cl][j4 + 1] = v.y; T[cl][j4 + 2] = v.z; T[cl][j4 + 3] = v.w;
    }
    __syncthreads();
    int ci_w = t & 127, jg = t >> 7;
    float sv = styles[b * 512 + ci0 + ci_w];
    unsigned short* op = xs + (((long)(b * 34 + (i + 1))) * 34 + 1) * 512 + ci0 + ci_w;
#pragma unroll
    for (int jj = 0; jj < 16; ++jj) {
        int j = jg * 16 + jj;
        op[(long)j * 512] = f2bf(T[ci_w][j] * sv);
    }
}

// K5: stage-1 implicit GEMM, 256x256 tile, BK=64, 8 waves (2Mx4N).
// R8-measured best (103.5 us, 4x reproduced): 2 phases/K-tile, 32 MFMA/phase,
// vmcnt(4) counted (never 0), lgkm drain + sched_barrier before MFMA cluster.
// blockIdx remap: Ntile pair of the same (par,Mtile) lands 8 dispatch slots
// apart -> same XCD under round-robin -> A-tile staged once into XCD L2.
// NOTE: 7 schedule/tile/occupancy variants (R5,R6,R9,R10,R13 + lgkm-removal,
// merged-stage) all regressed — this structure is the local optimum.
#define ST_A(kk) { GLDS16(xsB + sA0 + akt + (kk)*64, smp + nb + (kk)*16384 + t16); \
                   GLDS16(xsB + sA1 + akt + (kk)*64, smp + nb + (kk)*16384 + t16 + 8192); }
#define ST_B(kk) { GLDS16(wpB + sB0 + bkt + (kk)*64, smp + nb + 32768 + (kk)*16384 + t16); \
                   GLDS16(wpB + sB1 + bkt + (kk)*64, smp + nb + 32768 + (kk)*16384 + t16 + 8192); }
#define PHASE2(kk, STG, TAILBAR) { \
  _Pragma("unroll") for (int i = 0; i < 8; ++i) \
    av[i] = *(const bf16x8*)(smp + cb + (kk)*16384 + abase + (i*16)*64); \
  _Pragma("unroll") for (int j = 0; j < 4; ++j) \
    bv[j] = *(const bf16x8*)(smp + cb + (kk)*16384 + bbase + (j*16)*64); \
  STG; \
  __builtin_amdgcn_sched_barrier(0); \
  asm volatile("s_waitcnt vmcnt(4)" ::: "memory"); \
  __builtin_amdgcn_s_barrier(); \
  asm volatile("s_waitcnt lgkmcnt(0)" ::: "memory"); \
  __builtin_amdgcn_sched_barrier(0); \
  __builtin_amdgcn_s_setprio(1); \
  _Pragma("unroll") for (int i = 0; i < 8; ++i) \
    _Pragma("unroll") for (int j = 0; j < 4; ++j) \
      acc[i][j] = __builtin_amdgcn_mfma_f32_16x16x32_bf16(av[i], bv[j], acc[i][j], 0, 0, 0); \
  __builtin_amdgcn_s_setprio(0); \
  if (TAILBAR) __builtin_amdgcn_s_barrier(); }

__global__ __launch_bounds__(512, 2) void k_conv(const unsigned short* __restrict__ xs,
                                                 const unsigned short* __restrict__ wp,
                                                 unsigned short* __restrict__ y1) {
    extern __shared__ __align__(16) char smem[];
    const unsigned char* xsB = (const unsigned char*)xs;
    const unsigned char* wpB = (const unsigned char*)wp;
    char* smp = smem;

    // ---- XCD pair-scheduling remap: 552 dispatches -> (pr, nt) with the two
    // nt's of a pair 8 apart (same XCD, round-robin). pr in [0,276) par-major.
    int d = blockIdx.x;
    int pr, nt;
    if (d >= 544) { int r = d - 544; pr = 272 + (r & 3); nt = r >> 2; }
    else          { pr = (d >> 4) * 8 + (d & 7); nt = (d >> 3) & 1; }
    int par = pr / 69;
    int Mtile = pr - par * 69;
    int Ntile = nt;
    int a_par = par >> 1, c_par = par & 1;
    int ntaps = a_par ? (c_par ? 1 : 2) : (c_par ? 2 : 4);
    int tapofs = (par == 0) ? 0 : ((par == 1) ? 4 : ((par == 2) ? 6 : 8));
    int NKT = ntaps << 3;                 // K-tiles of 64 ci

    int tid = threadIdx.x;
    int lane = tid & 63, wave = tid >> 6;
    int wm = wave >> 2, wn = wave & 3;
    int lrow = lane & 15;
    int rchunk = (((lane >> 4) ^ ((lrow >> 1) & 3)) << 4);   // swizzled read chunk
    int abase = (wm * 128 + lrow) * 64 + rchunk;
    int bbase = 32768 + (wn * 64 + lrow) * 64 + rchunk;

    // staging source bases (rows tid>>2 and +128 of the 256-row tile)
    int srow = tid >> 2;
    int schunk = (((tid & 3) ^ ((tid >> 3) & 3)) << 4);      // inverse-swizzled source chunk
    int sA0, sA1;
    {
        unsigned gm = (unsigned)(Mtile * 256 + srow);
        if (gm > 17471u) gm = 17471u;
        unsigned b_ = gm / 1092u; unsigned pix = gm - b_ * 1092u;
        unsigned r = pix / 33u; unsigned s = pix - r * 33u;
        sA0 = (int)(((b_ * 34u + r) * 34u + s) << 10) + schunk;
        gm = (unsigned)(Mtile * 256 + srow + 128);
        if (gm > 17471u) gm = 17471u;
        b_ = gm / 1092u; pix = gm - b_ * 1092u;
        r = pix / 33u; s = pix - r * 33u;
        sA1 = (int)(((b_ * 34u + r) * 34u + s) << 10) + schunk;
    }
    int sB0 = ((Ntile * 256 + srow) << 10) + schunk;
    int sB1 = sB0 + (128 << 10);
    int t16 = tid << 4;

    f32x4 acc[8][4];
#pragma unroll
    for (int i = 0; i < 8; ++i)
#pragma unroll
        for (int j = 0; j < 4; ++j)
            acc[i][j] = (f32x4){0.f, 0.f, 0.f, 0.f};
    bf16x8 av[8], bv[4];

    auto mkA = [&](int kt) -> int {
        int tl = kt >> 3; if (tl >= ntaps) tl = ntaps - 1;
        int cib = kt & 7;
        int dio = a_par ? 1 : (c_par ? tl : (tl >> 1));
        int djo = c_par ? 1 : (a_par ? tl : (tl & 1));
        return dio * 34816 + djo * 1024 + cib * 128;
    };
    auto mkB = [&](int kt) -> long {
        int tl = kt >> 3; if (tl >= ntaps) tl = ntaps - 1;
        return (long)(tapofs + tl) * 524288 + (long)((kt & 7) * 128);
    };

    // prologue: stage K-tile 0 into buf0 (order: A0,B0,A1,B1 — matters for vmcnt)
    {
        int akt = mkA(0); long bkt = mkB(0); int nb = 0;
        ST_A(0); ST_B(0); ST_A(1); ST_B(1);
    }
    __builtin_amdgcn_sched_barrier(0);
    asm volatile("s_waitcnt vmcnt(4)" ::: "memory");   // k0 halves of tile 0 ready
    __builtin_amdgcn_s_barrier();

    int cur = 0;
    for (int kt = 0; kt < NKT; ++kt) {
        int akt = mkA(kt + 1);
        long bkt = mkB(kt + 1);
        int nb = (cur ^ 1) << 16;
        int cb = cur << 16;
        PHASE2(0, { ST_A(0); ST_B(0); }, 0)
        PHASE2(1, { ST_A(1); ST_B(1); }, 1)
        cur ^= 1;
    }

    // epilogue: clean unconditional ushort4 stores (junk cells are naturally 0).
#pragma unroll
    for (int mf = 0; mf < 8; ++mf) {
        int gm0 = Mtile * 256 + wm * 128 + mf * 16 + ((lane >> 4) << 2);
        if (gm0 < 17472) {
            unsigned ug = (unsigned)gm0;
            unsigned bb = ug / 1092u;
            int pix0 = (int)(ug - bb * 1092u);          // multiple of 4
            long rowb = ((long)((bb * 4u + par) * 512)) * SP;
#pragma unroll
            for (int nf = 0; nf < 4; ++nf) {
                int co = Ntile * 256 + wn * 64 + nf * 16 + lrow;
                unsigned short* dst = y1 + rowb + (long)co * SP + pix0;
                if (pix0 <= 1084) {
                    ushort4 pk;
                    pk.x = f2bf(acc[mf][nf][0]);
                    pk.y = f2bf(acc[mf][nf][1]);
                    pk.z = f2bf(acc[mf][nf][2]);
                    pk.w = f2bf(acc[mf][nf][3]);
                    *(ushort4*)dst = pk;
                } else if (pix0 == 1088) {
                    dst[0] = f2bf(acc[mf][nf][0]);
                }
            }
        }
    }
}

// K6: blur(4x4 bilinear, separable) + demod + noise + bias + leaky.
// LINEAR plane staging (R12-proven): yl[pl][p], p = r*33+s.
__global__ __launch_bounds__(256) void k_blur(const unsigned short* __restrict__ y1,
                                              const float* __restrict__ dcoefs,
                                              const float* __restrict__ bias,
                                              const float* __restrict__ noise,
                                              const float* __restrict__ nstr,
                                              float* __restrict__ out) {
    __shared__ float yl[4 * 1092];        // 17472 B
    int bid = blockIdx.x;                 // 2048 = 16 b * 128 cg
    int cg = bid & 127, b = bid >> 7;
    int t = threadIdx.x;
    int n = t & 63, mq = t >> 6;
    float ns = nstr[0];

    const float* npb = noise + b * 4096;

    int o = n & 1;
    int se = n >> 1;
    int sp_ = se - 1 + o;                 // -1 only for n==0
    float a0 = o ? 1.f : 3.f;
    float a1 = o ? 3.f : 1.f;

    for (int cc = 0; cc < 4; ++cc) {
        int co = cg * 4 + cc;
#pragma unroll
        for (int pl = 0; pl < 4; ++pl) {
            const unsigned short* src = y1 + ((long)((b * 4 + pl) * 512 + co)) * SP;
            float* dst = yl + pl * 1092;
            for (int it = t; it < 273; it += 256) {
                int p0 = it * 4;
                ushort4 v = *(const ushort4*)(src + p0);   // 8B aligned
                f32x4 fv;
                fv[0] = bf2f(v.x); fv[1] = bf2f(v.y);
                fv[2] = bf2f(v.z); fv[3] = bf2f(v.w);
                *(f32x4*)(dst + p0) = fv;                  // 16B aligned
            }
        }
        __syncthreads();

        float dc = dcoefs[b * 512 + co];
        float bi = bias[co];
        float* ob = out + ((long)(b * 512 + co)) * 4096;

        auto H = [&](int ap, int r) -> float {
            if ((unsigned)r > 32u) return 0.f;            // rows -1 / 33
            const float* pe = yl + (ap * 2) * 1092 + r * 33;
            const float* po = pe + 1092;
            float pov = (sp_ >= 0) ? po[sp_] : 0.f;       // col -1 (n==0 only)
            return a0 * pe[se] + a1 * pe[se + 1] + a1 * pov + a0 * po[sp_ + 1];
        };

        int m0 = mq * 16;                 // even
        int re = m0 >> 1;
        float he0 = H(0, re), he1 = H(0, re + 1);
        float ho0 = H(1, re - 1), ho1 = H(1, re);
#pragma unroll
        for (int k = 0; k < 16; k += 2) {
            int m = m0 + k;
            float ve = 3.f * he0 + he1 + ho0 + 3.f * ho1;
            float val = npb[m * 64 + n] * ns + ve * (0.0625f * dc);
            val = (val + bi) * 1.41421356237309515f;
            ob[m * 64 + n] = (val >= 0.f) ? val : 0.2f * val;
            float hn_o = H(1, re + 1);
            float vo = he0 + 3.f * he1 + 3.f * ho1 + hn_o;
            val = npb[(m + 1) * 64 + n] * ns + vo * (0.0625f * dc);
            val = (val + bi) * 1.41421356237309515f;
            ob[(m + 1) * 64 + n] = (val >= 0.f) ? val : 0.2f * val;
            ho0 = ho1; ho1 = hn_o;
            float hn_e = H(0, re + 2);
            he0 = he1; he1 = hn_e;
            re += 1;
        }
        __syncthreads();
    }
}

extern "C" void kernel_launch(void* const* d_in, const int* in_sizes, int n_in,
                              void* d_out, int out_size, void* d_ws, size_t ws_size,
                              hipStream_t stream) {
    (void)in_sizes; (void)n_in; (void)out_size;
    if (ws_size < (size_t)WS_NEED) return;   // workspace too small: fail cleanly
    const float* x      = (const float*)d_in[0];
    const float* w      = (const float*)d_in[1];
    const float* noise  = (const float*)d_in[2];
    const float* aw     = (const float*)d_in[3];
    const float* ab     = (const float*)d_in[4];
    const float* weight = (const float*)d_in[5];
    const float* bias   = (const float*)d_in[6];
    const float* nstr   = (const float*)d_in[7];
    float* out = (float*)d_out;
    char* ws = (char*)d_ws;
    float* styles          = (float*)(ws + O_STYLES);
    float* dcoefs          = (float*)(ws + O_DCOEF);
    unsigned short* xs     = (unsigned short*)(ws + O_XS);
    unsigned short* wp     = (unsigned short*)(ws + O_WP);
    unsigned short* y1     = (unsigned short*)(ws + O_Y1);
    float* wsq             = (float*)(ws + O_WSQ);   // overlapped with y1 head

    hipFuncSetAttribute((const void*)k_conv,
                        hipFuncAttributeMaxDynamicSharedMemorySize, 131072);

    k_prepA<<<1072, 256, 0, stream>>>(w, aw, ab, weight, styles, wsq, wp, xs);
    k_prepB<<<2080, 256, 0, stream>>>(styles, wsq, x, dcoefs, xs);
    k_conv <<<552,  512, 131072, stream>>>(xs, wp, y1);
    k_blur <<<2048, 256, 0, stream>>>(y1, dcoefs, bias, noise, nstr, out);
}